// Round 1
// baseline (40.784 us; speedup 1.0000x reference)
//
#include <hip/hip_runtime.h>

// Lattice geometry (fixed by the reference problem)
constexpr int TD = 32, XD = 16, YD = 16, ZD = 16;
constexpr int NSITE  = TD * XD * YD * ZD;   // 131072 = 2^17
constexpr int NBATCH = 16;
constexpr int BPT    = 8;                   // batches per thread
constexpr int NGROUP = NBATCH / BPT;        // 2

__global__ __launch_bounds__(256) void qshift_kernel(
    const float* __restrict__ field,   // [B, T,X,Y,Z, 3,4]
    const float* __restrict__ gauge,   // [4, T,X,Y,Z, 3,3]
    const int*   __restrict__ dir_p,   // single int
    float*       __restrict__ out)     // [B, T,X,Y,Z, 3,4]
{
    long tid = (long)blockIdx.x * blockDim.x + threadIdx.x;
    if (tid >= (long)NSITE * NGROUP) return;
    const int site = (int)(tid & (NSITE - 1));
    const int bgrp = (int)(tid >> 17);          // NSITE == 2^17
    const int b0   = bgrp * BPT;
    const int dir  = *dir_p;                    // wave-uniform

    const long fbase_site = (long)b0 * NSITE;   // in units of sites

    if (dir == 0) {
        // identity: straight copy of this thread's 8 batches
        const float4* src = (const float4*)field + (fbase_site + site) * 3;
        float4*       dst = (float4*)out        + (fbase_site + site) * 3;
        #pragma unroll
        for (int i = 0; i < BPT; ++i) {
            const long off = (long)i * NSITE * 3;
            dst[off + 0] = src[off + 0];
            dst[off + 1] = src[off + 1];
            dst[off + 2] = src[off + 2];
        }
        return;
    }

    const int d = (dir > 0) ? dir : -dir;       // 1..4
    const int a = d - 1;                        // lattice axis 0..3 (T,X,Y,Z)

    // axis shift/length in the linear site index (z innermost)
    const int shift = (a == 0) ? 12 : (a == 1) ? 8 : (a == 2) ? 4 : 0;
    const int len   = (a == 0) ? TD : 16;

    const int ca = (site >> shift) & (len - 1); // this dest's coord on axis a
    int cs;                                     // source coord on axis a
    bool transpose;
    if (dir > 0) {                              // out[i] = gp[i-1]^T @ f[i-1]
        cs = (ca == 0) ? (len - 1) : (ca - 1);
        transpose = true;
    } else {                                    // out[i] = gp[i] @ f[i+1]
        cs = (ca == len - 1) ? 0 : (ca + 1);
        transpose = false;
    }
    const int srcsite = site + ((cs - ca) << shift);
    const int gsite   = (dir > 0) ? srcsite : site;

    // load 3x3 gauge (scalar loads; 36B, unaligned to 16B — tiny traffic)
    const float* gp = gauge + ((long)a * NSITE + (long)gsite) * 9;
    float g0 = gp[0], g1 = gp[1], g2 = gp[2];
    float g3 = gp[3], g4 = gp[4], g5 = gp[5];
    float g6 = gp[6], g7 = gp[7], g8 = gp[8];

    // effective matrix m[row][col]: out[c][s] = sum_cc m[c][cc] * f[cc][s]
    float m00, m01, m02, m10, m11, m12, m20, m21, m22;
    if (transpose) {
        m00 = g0; m01 = g3; m02 = g6;
        m10 = g1; m11 = g4; m12 = g7;
        m20 = g2; m21 = g5; m22 = g8;
    } else {
        m00 = g0; m01 = g1; m02 = g2;
        m10 = g3; m11 = g4; m12 = g5;
        m20 = g6; m21 = g7; m22 = g8;
    }

    const float4* fsrc = (const float4*)field + (fbase_site + srcsite) * 3;
    float4*       dst  = (float4*)out        + (fbase_site + site) * 3;

    #pragma unroll
    for (int i = 0; i < BPT; ++i) {
        const long off = (long)i * NSITE * 3;
        const float4 f0 = fsrc[off + 0];   // color 0, spins 0..3
        const float4 f1 = fsrc[off + 1];   // color 1
        const float4 f2 = fsrc[off + 2];   // color 2
        float4 o0, o1, o2;
        o0.x = m00*f0.x + m01*f1.x + m02*f2.x;
        o0.y = m00*f0.y + m01*f1.y + m02*f2.y;
        o0.z = m00*f0.z + m01*f1.z + m02*f2.z;
        o0.w = m00*f0.w + m01*f1.w + m02*f2.w;
        o1.x = m10*f0.x + m11*f1.x + m12*f2.x;
        o1.y = m10*f0.y + m11*f1.y + m12*f2.y;
        o1.z = m10*f0.z + m11*f1.z + m12*f2.z;
        o1.w = m10*f0.w + m11*f1.w + m12*f2.w;
        o2.x = m20*f0.x + m21*f1.x + m22*f2.x;
        o2.y = m20*f0.y + m21*f1.y + m22*f2.y;
        o2.z = m20*f0.z + m21*f1.z + m22*f2.z;
        o2.w = m20*f0.w + m21*f1.w + m22*f2.w;
        dst[off + 0] = o0;
        dst[off + 1] = o1;
        dst[off + 2] = o2;
    }
}

extern "C" void kernel_launch(void* const* d_in, const int* in_sizes, int n_in,
                              void* d_out, int out_size, void* d_ws, size_t ws_size,
                              hipStream_t stream) {
    const float* field = (const float*)d_in[0];
    const float* gauge = (const float*)d_in[1];
    const int*   dirp  = (const int*)d_in[2];
    float*       outp  = (float*)d_out;

    const long nthreads = (long)NSITE * NGROUP;    // 262144
    const int  block = 256;
    const int  grid  = (int)((nthreads + block - 1) / block);  // 1024
    qshift_kernel<<<grid, block, 0, stream>>>(field, gauge, dirp, outp);
}